// Round 7
// baseline (142.142 us; speedup 1.0000x reference)
//
#include <hip/hip_runtime.h>

#define N_NODES 20000
#define N_EDGES 640000
#define HIDDEN  128
#define CAP     96        // max in-degree; Binomial(640K,1/20K) tail @96 ~ e^-45
#define DEG_PAD 16        // one counter per 64B line
#define GEMM_BLOCKS 313   // ceil(20000/16 rows / 4 waves)
#define FILL_BLOCKS 2500  // 640000 / 256

typedef unsigned short bf16_t;
typedef __attribute__((ext_vector_type(8))) short short8;    // 8 bf16 = 4 VGPRs
typedef __attribute__((ext_vector_type(4))) float floatx4;   // MFMA C/D

__device__ __forceinline__ bf16_t f2bf(float f) {
    union { float f; unsigned int i; } v; v.f = f;
    unsigned int x = v.i + 0x7FFFu + ((v.i >> 16) & 1u);   // RNE
    return (bf16_t)(x >> 16);
}
__device__ __forceinline__ float bflo(unsigned u) {
    union { unsigned i; float f; } v; v.i = u << 16; return v.f;
}
__device__ __forceinline__ float bfhi(unsigned u) {
    union { unsigned i; float f; } v; v.i = u & 0xFFFF0000u; return v.f;
}

// --- prep: feat fp32->bf16, zero deg, build B-fragment-packed [W_l | W_r] --
// Bp t = ((kt*16 + nt)*64 + lane)*8 + j  holds  B[k][n]:
//   k = kt*32 + (lane>>4)*8 + j   (K = 128, input dim)
//   n = nt*16 + (lane&15)         (N = 256: n<128 -> Y=W_l, n>=128 -> Z=W_r)
__global__ void prep_kernel(const float* __restrict__ feat,
                            const float* __restrict__ Wl,
                            const float* __restrict__ Wr,
                            bf16_t* __restrict__ feat_bf,
                            bf16_t* __restrict__ Bp,
                            int* __restrict__ deg) {
    int t = blockIdx.x * 256 + threadIdx.x;         // 0 .. 639999
    // feat convert: 640000 float4s exactly
    float4 v = ((const float4*)feat)[t];
    ushort4 o = { f2bf(v.x), f2bf(v.y), f2bf(v.z), f2bf(v.w) };
    ((ushort4*)feat_bf)[t] = o;
    // deg zero: 80000 int4s
    if (t < (N_NODES * DEG_PAD) / 4) {
        int4 zz = {0, 0, 0, 0};
        ((int4*)deg)[t] = zz;
    }
    // Bp pack: 32768 entries
    if (t < 2 * HIDDEN * HIDDEN) {
        int j    = t & 7;
        int lane = (t >> 3) & 63;
        int nt   = (t >> 9) & 15;
        int kt   = t >> 13;
        int n = nt * 16 + (lane & 15);
        int k = kt * 32 + (lane >> 4) * 8 + j;
        float w = (n < HIDDEN) ? Wl[n * HIDDEN + k] : Wr[(n - HIDDEN) * HIDDEN + k];
        Bp[t] = f2bf(w);
    }
}

// --- fused: MFMA GEMM (Y=feat@Wl^T bf16, Z=feat@Wr^T+b fp32)  ||  CSR fill -
// GEMM blocks [0,GEMM_BLOCKS) overlap with atomic-latency-bound fill blocks.
__global__ __launch_bounds__(256) void gemm_fill_kernel(
        const bf16_t* __restrict__ feat_bf,
        const bf16_t* __restrict__ Bp,
        const float* __restrict__ bl,
        const int* __restrict__ eidx,
        bf16_t* __restrict__ Y,
        float* __restrict__ Z,
        int* __restrict__ deg,
        int* __restrict__ bucket) {
    if (blockIdx.x < GEMM_BLOCKS) {
        int wid = blockIdx.x * 4 + (threadIdx.x >> 6);   // 16-row M-tile
        if (wid >= N_NODES / 16) return;
        int lane = threadIdx.x & 63;
        int m    = lane & 15;
        int quad = lane >> 4;
        int row0 = wid * 16;

        floatx4 acc[16];
        floatx4 zf = {0.f, 0.f, 0.f, 0.f};
#pragma unroll
        for (int nt = 0; nt < 16; ++nt) acc[nt] = zf;

        const short8* bp = (const short8*)Bp;
#pragma unroll
        for (int kt = 0; kt < 4; ++kt) {
            short8 afrag = *(const short8*)(feat_bf + (size_t)(row0 + m) * HIDDEN
                                            + kt * 32 + quad * 8);
#pragma unroll
            for (int nt = 0; nt < 16; ++nt) {
                short8 bfrag = bp[(kt * 16 + nt) * 64 + lane];
                acc[nt] = __builtin_amdgcn_mfma_f32_16x16x32_bf16(afrag, bfrag, acc[nt], 0, 0, 0);
            }
        }
        // C/D: col = lane&15, row = quad*4 + r  [m89-verified]
        int col = lane & 15;
#pragma unroll
        for (int nt = 0; nt < 8; ++nt) {            // Y half (W_l), bf16
#pragma unroll
            for (int r = 0; r < 4; ++r) {
                int row = row0 + quad * 4 + r;
                Y[(size_t)row * HIDDEN + nt * 16 + col] = f2bf(acc[nt][r]);
            }
        }
#pragma unroll
        for (int nt = 8; nt < 16; ++nt) {           // Z half (W_r) + bias, fp32
            float b = bl[(nt - 8) * 16 + col];
#pragma unroll
            for (int r = 0; r < 4; ++r) {
                int row = row0 + quad * 4 + r;
                Z[(size_t)row * HIDDEN + (nt - 8) * 16 + col] = acc[nt][r] + b;
            }
        }
    } else {
        int e = (blockIdx.x - GEMM_BLOCKS) * 256 + threadIdx.x;
        if (e >= N_EDGES) return;
        int src = eidx[e];
        int dst = eidx[N_EDGES + e];
        int pos = atomicAdd(&deg[dst * DEG_PAD], 1);
        if (pos < CAP) bucket[dst * CAP + pos] = src;
    }
}

// --- final: out[i] = mean_j Y[j] + Z[i]  (one wave64 per node) -------------
__global__ __launch_bounds__(256) void gather_final_kernel(
        const bf16_t* __restrict__ Y,
        const float* __restrict__ Z,
        const int* __restrict__ deg,
        const int* __restrict__ bucket,
        float* __restrict__ out) {
    int wid  = (blockIdx.x * 256 + threadIdx.x) >> 6;
    int lane = threadIdx.x & 63;
    if (wid >= N_NODES) return;
    int d_true = deg[wid * DEG_PAD];
    int d = min(d_true, CAP);
    const int* row = bucket + wid * CAP;
    const unsigned* y = (const unsigned*)Y;          // packed bf16 pairs
    float ax0=0,ay0=0, ax1=0,ay1=0, ax2=0,ay2=0, ax3=0,ay3=0;
    int i = 0;
    for (; i + 4 <= d; i += 4) {                     // 4 independent row-reads
        int4 s = *(const int4*)(row + i);
        unsigned u0 = y[s.x * 64 + lane];
        unsigned u1 = y[s.y * 64 + lane];
        unsigned u2 = y[s.z * 64 + lane];
        unsigned u3 = y[s.w * 64 + lane];
        ax0 += bflo(u0); ay0 += bfhi(u0);
        ax1 += bflo(u1); ay1 += bfhi(u1);
        ax2 += bflo(u2); ay2 += bfhi(u2);
        ax3 += bflo(u3); ay3 += bfhi(u3);
    }
    for (; i < d; ++i) {
        unsigned u = y[row[i] * 64 + lane];
        ax0 += bflo(u); ay0 += bfhi(u);
    }
    float inv = 1.0f / fmaxf((float)d_true, 1.0f);
    float2 z = ((const float2*)Z)[wid * 64 + lane];
    float2 r;
    r.x = (ax0 + ax1 + ax2 + ax3) * inv + z.x;
    r.y = (ay0 + ay1 + ay2 + ay3) * inv + z.y;
    ((float2*)out)[wid * 64 + lane] = r;
}

extern "C" void kernel_launch(void* const* d_in, const int* in_sizes, int n_in,
                              void* d_out, int out_size, void* d_ws, size_t ws_size,
                              hipStream_t stream) {
    const float* feat = (const float*)d_in[0];
    const int*   eidx = (const int*)d_in[1];
    const float* Wl   = (const float*)d_in[2];
    const float* bl   = (const float*)d_in[3];
    const float* Wr   = (const float*)d_in[4];
    float* out = (float*)d_out;

    // workspace layout (~29.5 MB; ws is 256 MiB)
    int*    deg     = (int*)d_ws;                              // 20000*16
    int*    bucket  = deg + N_NODES * DEG_PAD;                 // 20000*96
    bf16_t* Bp      = (bf16_t*)(bucket + N_NODES * CAP);       // 32768 bf16
    bf16_t* feat_bf = Bp + 2 * HIDDEN * HIDDEN;                // 20000*128 bf16
    bf16_t* Y       = feat_bf + (size_t)N_NODES * HIDDEN;      // 20000*128 bf16
    float*  Z       = (float*)(Y + (size_t)N_NODES * HIDDEN);  // 20000*128 fp32

    prep_kernel<<<2500, 256, 0, stream>>>(feat, Wl, Wr, feat_bf, Bp, deg);
    gemm_fill_kernel<<<GEMM_BLOCKS + FILL_BLOCKS, 256, 0, stream>>>(
        feat_bf, Bp, bl, eidx, Y, Z, deg, bucket);
    gather_final_kernel<<<(N_NODES * 64 + 255) / 256, 256, 0, stream>>>(
        Y, Z, deg, bucket, out);
}

// Round 8
// 136.314 us; speedup vs baseline: 1.0428x; 1.0428x over previous
//
#include <hip/hip_runtime.h>

#define N_NODES 20000
#define N_EDGES 640000
#define HIDDEN  128
#define CAP     96        // max in-degree; Binomial(640K,1/20K) tail @96 ~ e^-45
#define DEG_PAD 16        // one counter per 64B line

typedef unsigned short bf16_t;
typedef __attribute__((ext_vector_type(8))) short short8;            // 8 bf16
typedef __attribute__((ext_vector_type(8))) unsigned short ushort8_t; // 8 u16
typedef __attribute__((ext_vector_type(4))) float floatx4;            // MFMA C/D

__device__ __forceinline__ bf16_t f2bf(float f) {
    union { float f; unsigned int i; } v; v.f = f;
    unsigned int x = v.i + 0x7FFFu + ((v.i >> 16) & 1u);   // RNE
    return (bf16_t)(x >> 16);
}
__device__ __forceinline__ float bflo(unsigned u) {
    union { unsigned i; float f; } v; v.i = u << 16; return v.f;
}
__device__ __forceinline__ float bfhi(unsigned u) {
    union { unsigned i; float f; } v; v.i = u & 0xFFFF0000u; return v.f;
}

// --- k1: feat fp32->bf16  +  bucket fill  +  Bp weight pack ---------------
// All paths low-VGPR & latency-tolerant: no occupancy conflict (round-7 lesson).
// Bp t = ((kt*16 + nt)*64 + lane)*8 + j  holds  B[k][n]:
//   k = kt*32 + (lane>>4)*8 + j   (K = 128, input dim)
//   n = nt*16 + (lane&15)         (N = 256: n<128 -> W_l (Y), n>=128 -> W_r (Z))
__global__ __launch_bounds__(256) void prep_fill_kernel(
        const float* __restrict__ feat,
        const float* __restrict__ Wl,
        const float* __restrict__ Wr,
        const int* __restrict__ eidx,
        bf16_t* __restrict__ feat_bf,
        bf16_t* __restrict__ Bp,
        int* __restrict__ deg,                 // pre-zeroed, stride DEG_PAD
        unsigned short* __restrict__ bucket) {
    int t = blockIdx.x * 256 + threadIdx.x;    // 0 .. 639999 exactly
    // feat convert: 640000 float4s
    float4 v = ((const float4*)feat)[t];
    ushort4 o = { f2bf(v.x), f2bf(v.y), f2bf(v.z), f2bf(v.w) };
    ((ushort4*)feat_bf)[t] = o;
    // edge fill: one atomic slot-claim per edge
    int src = eidx[t];
    int dst = eidx[N_EDGES + t];
    int pos = atomicAdd(&deg[dst * DEG_PAD], 1);
    if (pos < CAP) bucket[dst * CAP + pos] = (unsigned short)src;
    // Bp pack: 32768 entries
    if (t < 2 * HIDDEN * HIDDEN) {
        int j    = t & 7;
        int lane = (t >> 3) & 63;
        int nt   = (t >> 9) & 15;
        int kt   = t >> 13;
        int n = nt * 16 + (lane & 15);
        int k = kt * 32 + (lane >> 4) * 8 + j;
        float w = (n < HIDDEN) ? Wl[n * HIDDEN + k] : Wr[(n - HIDDEN) * HIDDEN + k];
        Bp[t] = f2bf(w);
    }
}

// --- k2: MFMA GEMM  Y = feat@Wl^T (bf16),  Z = feat@Wr^T + b (fp32) --------
// A-frag: lane holds A[m=lane&15][k=kt*32+(lane>>4)*8+j]; B prepacked; 
// C/D: col=lane&15, row=(lane>>4)*4+r  [m89-verified]
__global__ __launch_bounds__(256) void gemm_kernel(
        const bf16_t* __restrict__ feat_bf,
        const bf16_t* __restrict__ Bp,
        const float* __restrict__ bl,
        bf16_t* __restrict__ Y,
        float* __restrict__ Z) {
    int wid = blockIdx.x * 4 + (threadIdx.x >> 6);   // 16-row M-tile
    if (wid >= N_NODES / 16) return;
    int lane = threadIdx.x & 63;
    int m    = lane & 15;
    int quad = lane >> 4;
    int row0 = wid * 16;

    floatx4 acc[16];
    floatx4 zf = {0.f, 0.f, 0.f, 0.f};
#pragma unroll
    for (int nt = 0; nt < 16; ++nt) acc[nt] = zf;

    const short8* bp = (const short8*)Bp;
#pragma unroll
    for (int kt = 0; kt < 4; ++kt) {
        short8 afrag = *(const short8*)(feat_bf + (size_t)(row0 + m) * HIDDEN
                                        + kt * 32 + quad * 8);
#pragma unroll
        for (int nt = 0; nt < 16; ++nt) {
            short8 bfrag = bp[(kt * 16 + nt) * 64 + lane];
            acc[nt] = __builtin_amdgcn_mfma_f32_16x16x32_bf16(afrag, bfrag, acc[nt], 0, 0, 0);
        }
    }
    int col = lane & 15;
#pragma unroll
    for (int nt = 0; nt < 8; ++nt) {            // Y half (W_l), bf16
#pragma unroll
        for (int r = 0; r < 4; ++r) {
            int row = row0 + quad * 4 + r;
            Y[(size_t)row * HIDDEN + nt * 16 + col] = f2bf(acc[nt][r]);
        }
    }
#pragma unroll
    for (int nt = 8; nt < 16; ++nt) {           // Z half (W_r) + bias, fp32
        float b = bl[(nt - 8) * 16 + col];
#pragma unroll
        for (int r = 0; r < 4; ++r) {
            int row = row0 + quad * 4 + r;
            Z[(size_t)row * HIDDEN + (nt - 8) * 16 + col] = acc[nt][r] + b;
        }
    }
}

// --- k3: out[i] = mean_{j in N(i)} Y[j] + Z[i]   (one wave64 per node) -----
// 8 neighbor indices per 16B ushort8 load; 8 independent Y-row gathers in flight.
__global__ __launch_bounds__(256) void gather_final_kernel(
        const bf16_t* __restrict__ Y,
        const float* __restrict__ Z,
        const int* __restrict__ deg,
        const unsigned short* __restrict__ bucket,
        float* __restrict__ out) {
    int wid  = (blockIdx.x * 256 + threadIdx.x) >> 6;
    int lane = threadIdx.x & 63;
    if (wid >= N_NODES) return;
    int d_true = deg[wid * DEG_PAD];
    int d = min(d_true, CAP);
    const unsigned short* row = bucket + wid * CAP;   // 192B-aligned
    const unsigned* y = (const unsigned*)Y;           // packed bf16 pairs
    float ax0=0,ay0=0, ax1=0,ay1=0, ax2=0,ay2=0, ax3=0,ay3=0;
    int i = 0;
    for (; i + 8 <= d; i += 8) {
        ushort8_t s = *(const ushort8_t*)(row + i);   // one 16B load, 8 nbrs
        unsigned u0 = y[(int)s[0] * 64 + lane];
        unsigned u1 = y[(int)s[1] * 64 + lane];
        unsigned u2 = y[(int)s[2] * 64 + lane];
        unsigned u3 = y[(int)s[3] * 64 + lane];
        unsigned u4 = y[(int)s[4] * 64 + lane];
        unsigned u5 = y[(int)s[5] * 64 + lane];
        unsigned u6 = y[(int)s[6] * 64 + lane];
        unsigned u7 = y[(int)s[7] * 64 + lane];
        ax0 += bflo(u0); ay0 += bfhi(u0);
        ax1 += bflo(u1); ay1 += bfhi(u1);
        ax2 += bflo(u2); ay2 += bfhi(u2);
        ax3 += bflo(u3); ay3 += bfhi(u3);
        ax0 += bflo(u4); ay0 += bfhi(u4);
        ax1 += bflo(u5); ay1 += bfhi(u5);
        ax2 += bflo(u6); ay2 += bfhi(u6);
        ax3 += bflo(u7); ay3 += bfhi(u7);
    }
    for (; i < d; ++i) {
        unsigned u = y[(int)row[i] * 64 + lane];
        ax0 += bflo(u); ay0 += bfhi(u);
    }
    float inv = 1.0f / fmaxf((float)d_true, 1.0f);
    float2 z = ((const float2*)Z)[wid * 64 + lane];
    float2 r;
    r.x = (ax0 + ax1 + ax2 + ax3) * inv + z.x;
    r.y = (ay0 + ay1 + ay2 + ay3) * inv + z.y;
    ((float2*)out)[wid * 64 + lane] = r;
}

extern "C" void kernel_launch(void* const* d_in, const int* in_sizes, int n_in,
                              void* d_out, int out_size, void* d_ws, size_t ws_size,
                              hipStream_t stream) {
    const float* feat = (const float*)d_in[0];
    const int*   eidx = (const int*)d_in[1];
    const float* Wl   = (const float*)d_in[2];
    const float* bl   = (const float*)d_in[3];
    const float* Wr   = (const float*)d_in[4];
    float* out = (float*)d_out;

    // workspace layout (~25.6 MB; ws is 256 MiB); all sections 16B-aligned
    int*            deg     = (int*)d_ws;                                   // 20000*16 int
    unsigned short* bucket  = (unsigned short*)(deg + N_NODES * DEG_PAD);   // 20000*96 u16
    bf16_t*         Bp      = (bf16_t*)(bucket + (size_t)N_NODES * CAP);    // 32768 bf16
    bf16_t*         feat_bf = Bp + 2 * HIDDEN * HIDDEN;                     // 20000*128 bf16
    bf16_t*         Y       = feat_bf + (size_t)N_NODES * HIDDEN;           // 20000*128 bf16
    float*          Z       = (float*)(Y + (size_t)N_NODES * HIDDEN);       // 20000*128 fp32

    hipMemsetAsync(deg, 0, (size_t)N_NODES * DEG_PAD * sizeof(int), stream);

    prep_fill_kernel<<<N_EDGES / 256, 256, 0, stream>>>(
        feat, Wl, Wr, eidx, feat_bf, Bp, deg, bucket);
    gemm_kernel<<<(N_NODES / 16 + 3) / 4, 256, 0, stream>>>(feat_bf, Bp, bl, Y, Z);
    gather_final_kernel<<<(N_NODES * 64) / 256, 256, 0, stream>>>(Y, Z, deg, bucket, out);
}